// Round 1
// baseline (39.408 us; speedup 1.0000x reference)
//
#include <hip/hip_runtime.h>

// Chamfer distance: pts = img_render_points[0] (4096 x 2 f32),
//                   refs = ref_catheter_skeleton[1] (32768 x 2 f32, flip is neutral)
// out = sum_i min_j ||p_i - r_j|| + sum_j min_i ||p_i - r_j||
// Strategy: min over squared distances (sqrt is monotone), one sqrt per point.

constexpr int N_PTS = 4096;
constexpr int M_REF = 32768;
constexpr int SLICE = 1024;   // staged other-side points per block
constexpr int BLK   = 256;

// Block decomposition:
//  rows: 16 pt-chunks (256 pts each) x 32 ref-slices  = 512 blocks
//  cols: 128 ref-chunks (256 refs each) x 4 pt-slices = 512 blocks
__global__ __launch_bounds__(BLK) void chamfer_min_kernel(
    const float2* __restrict__ pts,
    const float2* __restrict__ refs,
    unsigned int* __restrict__ rowmin,
    unsigned int* __restrict__ colmin)
{
    __shared__ float4 sh[SLICE / 2];   // 1024 float2 = 512 float4 = 8 KB
    const int tid = threadIdx.x;
    const int b   = blockIdx.x;

    const float2* own;
    const float2* oth;
    unsigned int* omin;
    int ownIdx, othBase;
    if (b < 512) {                       // row direction: own = pts
        const int chunk = b & 15, slice = b >> 4;
        own = pts;  oth = refs; omin = rowmin;
        ownIdx  = chunk * BLK + tid;
        othBase = slice * SLICE;
    } else {                             // col direction: own = refs
        const int bb = b - 512;
        const int chunk = bb & 127, slice = bb >> 7;
        own = refs; oth = pts;  omin = colmin;
        ownIdx  = chunk * BLK + tid;
        othBase = slice * SLICE;
    }

    // Stage SLICE other-side points into LDS (coalesced float4 loads).
    const float4* src = (const float4*)(oth + othBase);
    sh[tid]       = src[tid];
    sh[tid + 256] = src[tid + 256];
    __syncthreads();

    const float2 p = own[ownIdx];
    const float px = p.x, py = p.y;
    float m0 = 3.0e38f, m1 = 3.0e38f, m2 = 3.0e38f, m3 = 3.0e38f;

    #pragma unroll 4
    for (int k = 0; k < SLICE / 2; k += 2) {
        const float4 v0 = sh[k];         // broadcast reads (uniform addr, no conflict)
        const float4 v1 = sh[k + 1];
        float dx, dy;
        dx = px - v0.x; dy = py - v0.y; m0 = fminf(m0, fmaf(dx, dx, dy * dy));
        dx = px - v0.z; dy = py - v0.w; m1 = fminf(m1, fmaf(dx, dx, dy * dy));
        dx = px - v1.x; dy = py - v1.y; m2 = fminf(m2, fmaf(dx, dx, dy * dy));
        dx = px - v1.z; dy = py - v1.w; m3 = fminf(m3, fmaf(dx, dx, dy * dy));
    }
    const float m = fminf(fminf(m0, m1), fminf(m2, m3));
    // Nonnegative floats: uint bitcast preserves ordering.
    atomicMin(&omin[ownIdx], __float_as_uint(m));
}

__global__ __launch_bounds__(256) void chamfer_reduce_kernel(
    const unsigned int* __restrict__ mins, int n, float* __restrict__ out)
{
    __shared__ float ssum[4];
    const int gid = blockIdx.x * blockDim.x + threadIdx.x;
    float d = 0.0f;
    if (gid < n) {
        const float sq = __uint_as_float(mins[gid]);
        d = sqrtf(fmaxf(sq, 1e-12f));
    }
    #pragma unroll
    for (int off = 32; off > 0; off >>= 1)
        d += __shfl_down(d, off, 64);
    const int lane = threadIdx.x & 63, wave = threadIdx.x >> 6;
    if (lane == 0) ssum[wave] = d;
    __syncthreads();
    if (threadIdx.x == 0) {
        atomicAdd(out, ssum[0] + ssum[1] + ssum[2] + ssum[3]);
    }
}

extern "C" void kernel_launch(void* const* d_in, const int* in_sizes, int n_in,
                              void* d_out, int out_size, void* d_ws, size_t ws_size,
                              hipStream_t stream) {
    const float2* pts  = (const float2*)d_in[0];              // circle 0 (offset 0)
    const float2* refs = ((const float2*)d_in[1]) + M_REF;    // last (=2nd) skeleton slice
    unsigned int* rowmin = (unsigned int*)d_ws;               // [N_PTS]
    unsigned int* colmin = rowmin + N_PTS;                    // [M_REF]
    float* out = (float*)d_out;

    // Zero the scalar output; init min arrays to 0x7F7F7F7F (huge as float-bits).
    hipMemsetAsync(out, 0, sizeof(float), stream);
    hipMemsetAsync(rowmin, 0x7F, (size_t)(N_PTS + M_REF) * sizeof(unsigned int), stream);

    chamfer_min_kernel<<<1024, BLK, 0, stream>>>(pts, refs, rowmin, colmin);

    const int n = N_PTS + M_REF;                               // 36864 (contiguous)
    chamfer_reduce_kernel<<<n / 256, 256, 0, stream>>>(rowmin, n, out);
}